// Round 1
// baseline (1808.535 us; speedup 1.0000x reference)
//
#include <hip/hip_runtime.h>
#include <hip/hip_bf16.h>
#include <cmath>

// ---- problem constants ----
#define B_     8192
#define INF_   16
#define LAT_   128
#define HID_   1024
#define CS_    6540
#define XCOLS_ 145          // IN_F + LAT + 1
#define MK_    6528         // M*K coeff columns
#define NW_    1088         // M = (IN_F+1)*OUT_F
#define KP_    6656         // CS padded to mult of 128 (K of GEMM3, N of GEMM2)
#define N3_    6528         // GEMM3 N (coeff cols), = 51*128 = 68*96

typedef _Float16 f16;
typedef _Float16 f16x8 __attribute__((ext_vector_type(8)));
typedef float    f32x4 __attribute__((ext_vector_type(4)));

// ---------------------------------------------------------------------------
// convert z = x[:, 17:145] -> f16
__global__ __launch_bounds__(256) void zh_kernel(const float* __restrict__ x,
                                                 f16* __restrict__ zh) {
  int t = blockIdx.x * 256 + threadIdx.x;       // 8192*128 total
  int b = t >> 7, j = t & 127;
  zh[t] = (f16)x[(size_t)b * XCOLS_ + 17 + j];
}

// ---------------------------------------------------------------------------
// transpose-convert fp32 src[K][Ns] -> f16 dst[Np][Kp]  (dst[n][k] = src[k][n])
// zero-pads k>=Ks and n>=Nlim.
__global__ __launch_bounds__(256) void tconv_kernel(const float* __restrict__ src,
                                                    f16* __restrict__ dst,
                                                    int Ks, int Ns, int Nlim,
                                                    int Kp, int Np) {
  __shared__ float tile[64][65];
  int k0 = blockIdx.x * 64, n0 = blockIdx.y * 64;
  int tx = threadIdx.x & 63, ty = threadIdx.x >> 6;
#pragma unroll
  for (int i = 0; i < 16; ++i) {
    int r = i * 4 + ty;                          // k
    int gk = k0 + r, gn = n0 + tx;
    tile[r][tx] = (gk < Ks && gn < Nlim) ? src[(size_t)gk * Ns + gn] : 0.f;
  }
  __syncthreads();
#pragma unroll
  for (int i = 0; i < 16; ++i) {
    int n = i * 4 + ty;
    int gn = n0 + n, gk = k0 + tx;
    if (gn < Np && gk < Kp) dst[(size_t)gn * Kp + gk] = (f16)tile[tx][n];
  }
}

// ---------------------------------------------------------------------------
// global_load_lds staging of a ROWS x 64 f16 tile (row-major, contiguous LDS)
template <int ROWS>
__device__ __forceinline__ void stage_tile(const f16* __restrict__ src, int ld,
                                           int row0, int k0, f16* lds, int tid) {
  constexpr int ISSUES = ROWS / 32;              // (ROWS*128 B) / (256 lanes * 16 B)
  const int l = tid & 63, w = tid >> 6;
#pragma unroll
  for (int i = 0; i < ISSUES; ++i) {
    int chunk = i * 4096 + w * 1024;             // wave-uniform byte offset in LDS
    int o = chunk + l * 16;                      // this lane's byte offset
    int r = o >> 7;                              // 128 B per row (64 f16)
    int c = (o & 127) >> 1;
    const f16* g = src + (size_t)(row0 + r) * ld + k0 + c;
    __builtin_amdgcn_global_load_lds(
        (const __attribute__((address_space(1))) void*)g,
        (__attribute__((address_space(3))) void*)(lds + (chunk >> 1)),
        16, 0, 0);
  }
}

// ---------------------------------------------------------------------------
// NT GEMM: A (M x K, f16, row-major) @ Bt (N x K, f16, row-major)^T
// BM=128, BK=64, 4 waves (2x2), 16x16x32 f16 MFMA.
// EPI 0: out = tanh(acc + bias)  stored f16 (bias zero for col >= blim)
// EPI 1: fused coeff*v contraction -> w  (BN must be multiple of 6)
template <int BN, int EPI>
__global__ __launch_bounds__(256) void gemm_nt(
    const f16* __restrict__ A, int lda, const f16* __restrict__ Bt, int ldb,
    const float* __restrict__ bias, int blim, f16* __restrict__ outh, int ldo,
    float* __restrict__ w, const float* __restrict__ vv, int Ksteps, int nbn) {
  constexpr int NI = BN / 32;                    // col frags per wave (3 or 4)
  constexpr int WCOL = BN / 2;                   // wave col span (48 or 64)
  constexpr int STAGE = (128 + BN) * 64 * 2;
  constexpr int EPIB = (EPI == 1) ? 128 * 97 * 4 : 0;
  constexpr int SMEM = STAGE > EPIB ? STAGE : EPIB;
  __shared__ __align__(16) unsigned char smem[SMEM];
  f16* As = (f16*)smem;
  f16* Bs = As + 128 * 64;

  const int tid = threadIdx.x;
  const int l = tid & 63, wid = tid >> 6;
  const int wr = wid >> 1, wc = wid & 1;
  const int l15 = l & 15, lg = l >> 4;
  const int bm = blockIdx.x / nbn, bn = blockIdx.x % nbn;
  const int m0 = bm * 128, n0 = bn * BN;

  f32x4 acc[4][NI];
#pragma unroll
  for (int mi = 0; mi < 4; ++mi)
#pragma unroll
    for (int ni = 0; ni < NI; ++ni) acc[mi][ni] = (f32x4){0.f, 0.f, 0.f, 0.f};

  for (int ks = 0; ks < Ksteps; ++ks) {
    const int k0 = ks * 64;
    stage_tile<128>(A, lda, m0, k0, As, tid);
    stage_tile<BN>(Bt, ldb, n0, k0, Bs, tid);
    __syncthreads();                              // drains vmcnt before use
#pragma unroll
    for (int kk = 0; kk < 64; kk += 32) {
      f16x8 af[4];
#pragma unroll
      for (int mi = 0; mi < 4; ++mi)
        af[mi] = *(const f16x8*)(As + (wr * 64 + mi * 16 + l15) * 64 + kk + lg * 8);
#pragma unroll
      for (int ni = 0; ni < NI; ++ni) {
        f16x8 bf = *(const f16x8*)(Bs + (wc * WCOL + ni * 16 + l15) * 64 + kk + lg * 8);
#pragma unroll
        for (int mi = 0; mi < 4; ++mi)
          acc[mi][ni] = __builtin_amdgcn_mfma_f32_16x16x32_f16(af[mi], bf,
                                                               acc[mi][ni], 0, 0, 0);
      }
    }
    __syncthreads();
  }

  if constexpr (EPI == 0) {
    // C/D layout: col = lane&15, row = (lane>>4)*4 + j  [m89/m91 verified]
#pragma unroll
    for (int ni = 0; ni < NI; ++ni) {
      int col = n0 + wc * WCOL + ni * 16 + l15;
      float bv = (col < blim) ? bias[col] : 0.f;
#pragma unroll
      for (int mi = 0; mi < 4; ++mi) {
        int r0 = m0 + wr * 64 + mi * 16 + lg * 4;
#pragma unroll
        for (int j = 0; j < 4; ++j)
          outh[(size_t)(r0 + j) * ldo + col] = (f16)tanhf(acc[mi][ni][j] + bv);
      }
    }
  } else {
    // fused epilogue: w[b, m] = sum_k (C[b, m*6+k] + b3) * v[b, k]
    float* Cl = (float*)smem;                     // 128 x 96 (stride 97)
#pragma unroll
    for (int ni = 0; ni < NI; ++ni) {
      int cl = wc * WCOL + ni * 16 + l15;
      float bv = bias[n0 + cl];
#pragma unroll
      for (int mi = 0; mi < 4; ++mi) {
        int rl = wr * 64 + mi * 16 + lg * 4;
#pragma unroll
        for (int j = 0; j < 4; ++j) Cl[(rl + j) * 97 + cl] = acc[mi][ni][j] + bv;
      }
    }
    __syncthreads();
#pragma unroll
    for (int it = 0; it < 8; ++it) {
      int idx = it * 256 + tid;                   // 128 rows x 16 groups
      int r = idx >> 4, g = idx & 15;
      const float* vr = vv + (size_t)(m0 + r) * 8;
      float s = 0.f;
#pragma unroll
      for (int k = 0; k < 6; ++k) s += Cl[r * 97 + g * 6 + k] * vr[k];
      w[(size_t)(m0 + r) * NW_ + bn * 16 + g] = s;
    }
  }
}

// ---------------------------------------------------------------------------
// dil/shift columns (6528..6539) of GEMM3 in fp32, then v vector.
__global__ __launch_bounds__(256) void sv_kernel(const f16* __restrict__ h2,
                                                 const float* __restrict__ W3,
                                                 const float* __restrict__ b3,
                                                 const float* __restrict__ x,
                                                 float* __restrict__ vv) {
  __shared__ float red[12][4];
  int b = blockIdx.x, tid = threadIdx.x;
  int lane = tid & 63, wid = tid >> 6;
  float p[12];
#pragma unroll
  for (int j = 0; j < 12; ++j) p[j] = 0.f;
  for (int k = tid; k < CS_; k += 256) {
    float hv = (float)h2[(size_t)b * KP_ + k];
    const float* wr = W3 + (size_t)k * CS_ + MK_;
#pragma unroll
    for (int j = 0; j < 12; ++j) p[j] += hv * wr[j];
  }
#pragma unroll
  for (int j = 0; j < 12; ++j) {
    float v = p[j];
    for (int off = 32; off; off >>= 1) v += __shfl_down(v, off, 64);
    if (lane == 0) red[j][wid] = v;
  }
  __syncthreads();
  if (tid < 6) {
    int j = tid;
    float dil = red[j][0] + red[j][1] + red[j][2] + red[j][3] + b3[MK_ + j];
    float sh  = red[6 + j][0] + red[6 + j][1] + red[6 + j][2] + red[6 + j][3] + b3[MK_ + 6 + j];
    float s = x[(size_t)(B_ - 1) * XCOLS_ + INF_];
    float sv = s * dil + sh;
    vv[(size_t)b * 8 + j] = (j < 3) ? cosf(sv * (float)j) : sinf(sv * (float)(j - 3));
  }
}

// ---------------------------------------------------------------------------
// out[b,o] = sum_i inp[b,i] * w[b, i*64+o] + w[b, 1024+o]
__global__ __launch_bounds__(256) void out_kernel(const float* __restrict__ x,
                                                  const float* __restrict__ w,
                                                  float* __restrict__ out) {
  int wid = threadIdx.x >> 6, lane = threadIdx.x & 63;
  int b = blockIdx.x * 4 + wid;
  const float* wr = w + (size_t)b * NW_;
  const float* xr = x + (size_t)b * XCOLS_;
  float acc = wr[1024 + lane];
#pragma unroll
  for (int i = 0; i < 16; ++i) acc += xr[i] * wr[i * 64 + lane];
  out[(size_t)b * 64 + lane] = acc;
}

// ---------------------------------------------------------------------------
extern "C" void kernel_launch(void* const* d_in, const int* in_sizes, int n_in,
                              void* d_out, int out_size, void* d_ws, size_t ws_size,
                              hipStream_t stream) {
  const float* x  = (const float*)d_in[0];
  const float* W1 = (const float*)d_in[1];
  const float* b1 = (const float*)d_in[2];
  const float* W2 = (const float*)d_in[3];
  const float* b2 = (const float*)d_in[4];
  const float* W3 = (const float*)d_in[5];
  const float* b3 = (const float*)d_in[6];
  float* out = (float*)d_out;

  char* ws = (char*)d_ws;
  f16*   zh  = (f16*)(ws);                        //  2,097,152 B
  f16*   W1t = (f16*)(ws + 2097152);              //    262,144 B  (1024 x 128)
  f16*   W2t = (f16*)(ws + 2359296);              // 13,631,488 B  (6656 x 1024)
  f16*   W3t = (f16*)(ws + 15990784);             // 86,900,736 B  (6528 x 6656)
  f16*   h1  = (f16*)(ws + 102891520);            // 16,777,216 B  (8192 x 1024)
  f16*   h2  = (f16*)(ws + 119668736);            //109,051,904 B  (8192 x 6656)
  float* vv  = (float*)(ws + 228720640);          //    262,144 B  (8192 x 8)
  float* w   = (float*)(ws + 228982784);          // 35,651,584 B  (8192 x 1088)
  // total 264,634,368 B

  zh_kernel<<<4096, 256, 0, stream>>>(x, zh);
  tconv_kernel<<<dim3(2, 16),    256, 0, stream>>>(W1, W1t, 128,  1024, 1024, 128,  1024);
  tconv_kernel<<<dim3(16, 104),  256, 0, stream>>>(W2, W2t, 1024, CS_,  CS_,  1024, KP_);
  tconv_kernel<<<dim3(104, 102), 256, 0, stream>>>(W3, W3t, CS_,  CS_,  N3_,  KP_,  N3_);

  // GEMM1: h1 = tanh(zh @ W1 + b1)   (M=8192, N=1024, K=128)
  gemm_nt<128, 0><<<(1024 / 128) * (B_ / 128), 256, 0, stream>>>(
      zh, 128, W1t, 128, b1, 1024, h1, 1024, nullptr, nullptr, 2, 1024 / 128);
  // GEMM2: h2 = tanh(h1 @ W2 + b2)   (M=8192, N=6656pad, K=1024)
  gemm_nt<128, 0><<<(KP_ / 128) * (B_ / 128), 256, 0, stream>>>(
      h1, 1024, W2t, 1024, b2, CS_, h2, KP_, nullptr, nullptr, 16, KP_ / 128);
  // dilation/shift + v
  sv_kernel<<<B_, 256, 0, stream>>>(h2, W3, b3, x, vv);
  // GEMM3 fused: w = (h2 @ W3[:, :6528] + b3) contracted with v
  gemm_nt<96, 1><<<(N3_ / 96) * (B_ / 128), 256, 0, stream>>>(
      h2, KP_, W3t, KP_, b3, N3_, nullptr, 0, w, vv, KP_ / 64, N3_ / 96);
  // final einsum
  out_kernel<<<B_ / 4, 256, 0, stream>>>(x, w, out);
}

// Round 2
// 1721.998 us; speedup vs baseline: 1.0503x; 1.0503x over previous
//
#include <hip/hip_runtime.h>
#include <hip/hip_bf16.h>
#include <cmath>

// ---- problem constants ----
#define B_     8192
#define INF_   16
#define LAT_   128
#define HID_   1024
#define CS_    6540
#define XCOLS_ 145          // IN_F + LAT + 1
#define MK_    6528         // M*K coeff columns
#define NW_    1088         // M = (IN_F+1)*OUT_F
#define KP_    6656         // CS padded to mult of 128 (K of GEMM3, N of GEMM2)
#define N3_    6528         // GEMM3 N (coeff cols), = 51*128 = 68*96

typedef _Float16 f16;
typedef _Float16 f16x8 __attribute__((ext_vector_type(8)));
typedef float    f32x4 __attribute__((ext_vector_type(4)));

// ---------------------------------------------------------------------------
// convert z = x[:, 17:145] -> f16
__global__ __launch_bounds__(256) void zh_kernel(const float* __restrict__ x,
                                                 f16* __restrict__ zh) {
  int t = blockIdx.x * 256 + threadIdx.x;       // 8192*128 total
  int b = t >> 7, j = t & 127;
  zh[t] = (f16)x[(size_t)b * XCOLS_ + 17 + j];
}

// ---------------------------------------------------------------------------
// transpose-convert fp32 src[K][Ns] -> f16 dst[Np][Kp]  (dst[n][k] = src[k][n])
// zero-pads k>=Ks and n>=Nlim.
__global__ __launch_bounds__(256) void tconv_kernel(const float* __restrict__ src,
                                                    f16* __restrict__ dst,
                                                    int Ks, int Ns, int Nlim,
                                                    int Kp, int Np) {
  __shared__ float tile[64][65];
  int k0 = blockIdx.x * 64, n0 = blockIdx.y * 64;
  int tx = threadIdx.x & 63, ty = threadIdx.x >> 6;
#pragma unroll
  for (int i = 0; i < 16; ++i) {
    int r = i * 4 + ty;                          // k
    int gk = k0 + r, gn = n0 + tx;
    tile[r][tx] = (gk < Ks && gn < Nlim) ? src[(size_t)gk * Ns + gn] : 0.f;
  }
  __syncthreads();
#pragma unroll
  for (int i = 0; i < 16; ++i) {
    int n = i * 4 + ty;
    int gn = n0 + n, gk = k0 + tx;
    if (gn < Np && gk < Kp) dst[(size_t)gn * Kp + gk] = (f16)tile[tx][n];
  }
}

// ---------------------------------------------------------------------------
// global_load_lds staging of a ROWS x 64 f16 tile.
// LDS layout is XOR-swizzled: phys_byte = logical_byte ^ ((row&7)<<4).
// Dest stays LINEAR (global_load_lds requires base + lane*16); instead the
// GLOBAL source column is inverse-swizzled (XOR is an involution) so that the
// data for logical position p lands at phys position o.  [rule #21]
template <int ROWS>
__device__ __forceinline__ void stage_tile(const f16* __restrict__ src, int ld,
                                           int row0, int k0, f16* lds, int tid) {
  constexpr int ISSUES = ROWS / 32;              // (ROWS*128 B) / (256 lanes * 16 B)
  const int l = tid & 63, w = tid >> 6;
#pragma unroll
  for (int i = 0; i < ISSUES; ++i) {
    int chunk = i * 4096 + w * 1024;             // wave-uniform byte offset in LDS
    int o = chunk + l * 16;                      // this lane's phys byte offset
    int r = o >> 7;                              // 128 B per row (64 f16)
    int p = o ^ ((r & 7) << 4);                  // logical byte position
    int c = (p & 127) >> 1;                      // f16 col within row
    const f16* g = src + (size_t)(row0 + r) * ld + k0 + c;
    __builtin_amdgcn_global_load_lds(
        (const __attribute__((address_space(1))) void*)g,
        (__attribute__((address_space(3))) void*)(lds + (chunk >> 1)),
        16, 0, 0);
  }
}

// swizzled fragment read: 16 B at logical (row, kbyte)
__device__ __forceinline__ f16x8 frag_ld(const f16* base, int row, int kb) {
  int off = row * 128 + (kb ^ ((row & 7) << 4));
  return *(const f16x8*)((const char*)base + off);
}

// ---------------------------------------------------------------------------
// NT GEMM: A (M x K, f16, row-major) @ Bt (N x K, f16, row-major)^T
// BM=128, BK=64, 4 waves (2x2), 16x16x32 f16 MFMA.
// EPI 0: out = tanh(acc + bias)  stored f16 (bias zero for col >= blim)
// EPI 1: fused coeff*v contraction -> w  (BN must be multiple of 6)
template <int BN, int EPI>
__global__ __launch_bounds__(256) void gemm_nt(
    const f16* __restrict__ A, int lda, const f16* __restrict__ Bt, int ldb,
    const float* __restrict__ bias, int blim, f16* __restrict__ outh, int ldo,
    float* __restrict__ w, const float* __restrict__ vv, int Ksteps, int nbn) {
  constexpr int NI = BN / 32;                    // col frags per wave (3 or 4)
  constexpr int WCOL = BN / 2;                   // wave col span (48 or 64)
  constexpr int STAGE = (128 + BN) * 64 * 2;
  constexpr int EPIB = (EPI == 1) ? 128 * 97 * 4 : 0;
  constexpr int SMEM = STAGE > EPIB ? STAGE : EPIB;
  __shared__ __align__(16) unsigned char smem[SMEM];
  f16* As = (f16*)smem;
  f16* Bs = As + 128 * 64;

  const int tid = threadIdx.x;
  const int l = tid & 63, wid = tid >> 6;
  const int wr = wid >> 1, wc = wid & 1;
  const int l15 = l & 15, lg = l >> 4;
  const int bm = blockIdx.x / nbn, bn = blockIdx.x % nbn;
  const int m0 = bm * 128, n0 = bn * BN;

  f32x4 acc[4][NI];
#pragma unroll
  for (int mi = 0; mi < 4; ++mi)
#pragma unroll
    for (int ni = 0; ni < NI; ++ni) acc[mi][ni] = (f32x4){0.f, 0.f, 0.f, 0.f};

  for (int ks = 0; ks < Ksteps; ++ks) {
    const int k0 = ks * 64;
    stage_tile<128>(A, lda, m0, k0, As, tid);
    stage_tile<BN>(Bt, ldb, n0, k0, Bs, tid);
    __syncthreads();                              // drains vmcnt before use
#pragma unroll
    for (int kk = 0; kk < 64; kk += 32) {
      const int kb = (kk + lg * 8) * 2;           // byte offset of this lane's k
      f16x8 af[4];
#pragma unroll
      for (int mi = 0; mi < 4; ++mi)
        af[mi] = frag_ld(As, wr * 64 + mi * 16 + l15, kb);
#pragma unroll
      for (int ni = 0; ni < NI; ++ni) {
        f16x8 bf = frag_ld(Bs, wc * WCOL + ni * 16 + l15, kb);
#pragma unroll
        for (int mi = 0; mi < 4; ++mi)
          acc[mi][ni] = __builtin_amdgcn_mfma_f32_16x16x32_f16(af[mi], bf,
                                                               acc[mi][ni], 0, 0, 0);
      }
    }
    __syncthreads();
  }

  if constexpr (EPI == 0) {
    // C/D layout: col = lane&15, row = (lane>>4)*4 + j  [m89/m91 verified]
#pragma unroll
    for (int ni = 0; ni < NI; ++ni) {
      int col = n0 + wc * WCOL + ni * 16 + l15;
      float bv = (col < blim) ? bias[col] : 0.f;
#pragma unroll
      for (int mi = 0; mi < 4; ++mi) {
        int r0 = m0 + wr * 64 + mi * 16 + lg * 4;
#pragma unroll
        for (int j = 0; j < 4; ++j)
          outh[(size_t)(r0 + j) * ldo + col] = (f16)tanhf(acc[mi][ni][j] + bv);
      }
    }
  } else {
    // fused epilogue: w[b, m] = sum_k (C[b, m*6+k] + b3) * v[b, k]
    float* Cl = (float*)smem;                     // 128 x 96 (stride 97)
#pragma unroll
    for (int ni = 0; ni < NI; ++ni) {
      int cl = wc * WCOL + ni * 16 + l15;
      float bv = bias[n0 + cl];
#pragma unroll
      for (int mi = 0; mi < 4; ++mi) {
        int rl = wr * 64 + mi * 16 + lg * 4;
#pragma unroll
        for (int j = 0; j < 4; ++j) Cl[(rl + j) * 97 + cl] = acc[mi][ni][j] + bv;
      }
    }
    __syncthreads();
#pragma unroll
    for (int it = 0; it < 8; ++it) {
      int idx = it * 256 + tid;                   // 128 rows x 16 groups
      int r = idx >> 4, g = idx & 15;
      const float* vr = vv + (size_t)(m0 + r) * 8;
      float s = 0.f;
#pragma unroll
      for (int k = 0; k < 6; ++k) s += Cl[r * 97 + g * 6 + k] * vr[k];
      w[(size_t)(m0 + r) * NW_ + bn * 16 + g] = s;
    }
  }
}

// ---------------------------------------------------------------------------
// dil/shift columns (6528..6539) of GEMM3 in fp32, then v vector.
__global__ __launch_bounds__(256) void sv_kernel(const f16* __restrict__ h2,
                                                 const float* __restrict__ W3,
                                                 const float* __restrict__ b3,
                                                 const float* __restrict__ x,
                                                 float* __restrict__ vv) {
  __shared__ float red[12][4];
  int b = blockIdx.x, tid = threadIdx.x;
  int lane = tid & 63, wid = tid >> 6;
  float p[12];
#pragma unroll
  for (int j = 0; j < 12; ++j) p[j] = 0.f;
  for (int k = tid; k < CS_; k += 256) {
    float hv = (float)h2[(size_t)b * KP_ + k];
    const float* wr = W3 + (size_t)k * CS_ + MK_;
#pragma unroll
    for (int j = 0; j < 12; ++j) p[j] += hv * wr[j];
  }
#pragma unroll
  for (int j = 0; j < 12; ++j) {
    float v = p[j];
    for (int off = 32; off; off >>= 1) v += __shfl_down(v, off, 64);
    if (lane == 0) red[j][wid] = v;
  }
  __syncthreads();
  if (tid < 6) {
    int j = tid;
    float dil = red[j][0] + red[j][1] + red[j][2] + red[j][3] + b3[MK_ + j];
    float sh  = red[6 + j][0] + red[6 + j][1] + red[6 + j][2] + red[6 + j][3] + b3[MK_ + 6 + j];
    float s = x[(size_t)(B_ - 1) * XCOLS_ + INF_];
    float sv = s * dil + sh;
    vv[(size_t)b * 8 + j] = (j < 3) ? cosf(sv * (float)j) : sinf(sv * (float)(j - 3));
  }
}

// ---------------------------------------------------------------------------
// out[b,o] = sum_i inp[b,i] * w[b, i*64+o] + w[b, 1024+o]
__global__ __launch_bounds__(256) void out_kernel(const float* __restrict__ x,
                                                  const float* __restrict__ w,
                                                  float* __restrict__ out) {
  int wid = threadIdx.x >> 6, lane = threadIdx.x & 63;
  int b = blockIdx.x * 4 + wid;
  const float* wr = w + (size_t)b * NW_;
  const float* xr = x + (size_t)b * XCOLS_;
  float acc = wr[1024 + lane];
#pragma unroll
  for (int i = 0; i < 16; ++i) acc += xr[i] * wr[i * 64 + lane];
  out[(size_t)b * 64 + lane] = acc;
}

// ---------------------------------------------------------------------------
extern "C" void kernel_launch(void* const* d_in, const int* in_sizes, int n_in,
                              void* d_out, int out_size, void* d_ws, size_t ws_size,
                              hipStream_t stream) {
  const float* x  = (const float*)d_in[0];
  const float* W1 = (const float*)d_in[1];
  const float* b1 = (const float*)d_in[2];
  const float* W2 = (const float*)d_in[3];
  const float* b2 = (const float*)d_in[4];
  const float* W3 = (const float*)d_in[5];
  const float* b3 = (const float*)d_in[6];
  float* out = (float*)d_out;

  char* ws = (char*)d_ws;
  f16*   zh  = (f16*)(ws);                        //  2,097,152 B
  f16*   W1t = (f16*)(ws + 2097152);              //    262,144 B  (1024 x 128)
  f16*   W2t = (f16*)(ws + 2359296);              // 13,631,488 B  (6656 x 1024)
  f16*   W3t = (f16*)(ws + 15990784);             // 86,900,736 B  (6528 x 6656)
  f16*   h1  = (f16*)(ws + 102891520);            // 16,777,216 B  (8192 x 1024)
  f16*   h2  = (f16*)(ws + 119668736);            //109,051,904 B  (8192 x 6656)
  float* vv  = (float*)(ws + 228720640);          //    262,144 B  (8192 x 8)
  float* w   = (float*)(ws + 228982784);          // 35,651,584 B  (8192 x 1088)
  // total 264,634,368 B

  zh_kernel<<<4096, 256, 0, stream>>>(x, zh);
  tconv_kernel<<<dim3(2, 16),    256, 0, stream>>>(W1, W1t, 128,  1024, 1024, 128,  1024);
  tconv_kernel<<<dim3(16, 104),  256, 0, stream>>>(W2, W2t, 1024, CS_,  CS_,  1024, KP_);
  tconv_kernel<<<dim3(104, 102), 256, 0, stream>>>(W3, W3t, CS_,  CS_,  N3_,  KP_,  N3_);

  // GEMM1: h1 = tanh(zh @ W1 + b1)   (M=8192, N=1024, K=128)
  gemm_nt<128, 0><<<(1024 / 128) * (B_ / 128), 256, 0, stream>>>(
      zh, 128, W1t, 128, b1, 1024, h1, 1024, nullptr, nullptr, 2, 1024 / 128);
  // GEMM2: h2 = tanh(h1 @ W2 + b2)   (M=8192, N=6656pad, K=1024)
  gemm_nt<128, 0><<<(KP_ / 128) * (B_ / 128), 256, 0, stream>>>(
      h1, 1024, W2t, 1024, b2, CS_, h2, KP_, nullptr, nullptr, 16, KP_ / 128);
  // dilation/shift + v
  sv_kernel<<<B_, 256, 0, stream>>>(h2, W3, b3, x, vv);
  // GEMM3 fused: w = (h2 @ W3[:, :6528] + b3) contracted with v
  gemm_nt<96, 1><<<(N3_ / 96) * (B_ / 128), 256, 0, stream>>>(
      h2, KP_, W3t, KP_, b3, N3_, nullptr, 0, w, vv, KP_ / 64, N3_ / 96);
  // final einsum
  out_kernel<<<B_ / 4, 256, 0, stream>>>(x, w, out);
}

// Round 3
// 1395.850 us; speedup vs baseline: 1.2957x; 1.2337x over previous
//
#include <hip/hip_runtime.h>
#include <hip/hip_bf16.h>
#include <cmath>

// ---- problem constants ----
#define B_     8192
#define INF_   16
#define LAT_   128
#define HID_   1024
#define CS_    6540
#define XCOLS_ 145          // IN_F + LAT + 1
#define MK_    6528         // M*K coeff columns
#define NW_    1088         // M = (IN_F+1)*OUT_F
#define KP_    6656         // CS padded to mult of 128 (K of GEMM3, N of GEMM2)
#define N3_    6528         // GEMM3 N (coeff cols), = 51*128 = 34*192

typedef _Float16 f16;
typedef _Float16 f16x8 __attribute__((ext_vector_type(8)));
typedef float    f32x4 __attribute__((ext_vector_type(4)));

#define VMCNT(n) do { asm volatile("s_waitcnt vmcnt(" #n ")" ::: "memory"); \
                      __builtin_amdgcn_sched_barrier(0); } while (0)
#define LGKMCNT0 do { asm volatile("s_waitcnt lgkmcnt(0)" ::: "memory"); \
                      __builtin_amdgcn_sched_barrier(0); } while (0)

// ---------------------------------------------------------------------------
// convert z = x[:, 17:145] -> f16
__global__ __launch_bounds__(256) void zh_kernel(const float* __restrict__ x,
                                                 f16* __restrict__ zh) {
  int t = blockIdx.x * 256 + threadIdx.x;       // 8192*128 total
  int b = t >> 7, j = t & 127;
  zh[t] = (f16)x[(size_t)b * XCOLS_ + 17 + j];
}

// ---------------------------------------------------------------------------
// transpose-convert fp32 src[K][Ns] -> f16 dst[Np][Kp]  (dst[n][k] = src[k][n])
// zero-pads k>=Ks and n>=Nlim.
__global__ __launch_bounds__(256) void tconv_kernel(const float* __restrict__ src,
                                                    f16* __restrict__ dst,
                                                    int Ks, int Ns, int Nlim,
                                                    int Kp, int Np) {
  __shared__ float tile[64][65];
  int k0 = blockIdx.x * 64, n0 = blockIdx.y * 64;
  int tx = threadIdx.x & 63, ty = threadIdx.x >> 6;
#pragma unroll
  for (int i = 0; i < 16; ++i) {
    int r = i * 4 + ty;                          // k
    int gk = k0 + r, gn = n0 + tx;
    tile[r][tx] = (gk < Ks && gn < Nlim) ? src[(size_t)gk * Ns + gn] : 0.f;
  }
  __syncthreads();
#pragma unroll
  for (int i = 0; i < 16; ++i) {
    int n = i * 4 + ty;
    int gn = n0 + n, gk = k0 + tx;
    if (gn < Np && gk < Kp) dst[(size_t)gn * Kp + gk] = (f16)tile[tx][n];
  }
}

// ---------------------------------------------------------------------------
// Swizzled LDS tile helpers: phys_byte = logical_byte ^ ((row&7)<<4); rows are
// 64 f16 = 128 B. global_load_lds dest stays LINEAR; global source column is
// inverse-swizzled (XOR involution).  [rule #21]
__device__ __forceinline__ f16x8 frag_ld(const f16* base, int row, int kb) {
  int off = row * 128 + (kb ^ ((row & 7) << 4));
  return *(const f16x8*)((const char*)base + off);
}

// 256-thread staging (4-wave kernels)
template <int ROWS>
__device__ __forceinline__ void stage_tile(const f16* __restrict__ src, int ld,
                                           int row0, int k0, f16* lds, int tid) {
  constexpr int ISSUES = ROWS / 32;
  const int l = tid & 63, w = tid >> 6;
#pragma unroll
  for (int i = 0; i < ISSUES; ++i) {
    int chunk = i * 4096 + w * 1024;
    int o = chunk + l * 16;
    int r = o >> 7;
    int p = o ^ ((r & 7) << 4);
    int c = (p & 127) >> 1;
    const f16* g = src + (size_t)(row0 + r) * ld + k0 + c;
    __builtin_amdgcn_global_load_lds(
        (const __attribute__((address_space(1))) void*)g,
        (__attribute__((address_space(3))) void*)(lds + (chunk >> 1)),
        16, 0, 0);
  }
}

// 512-thread staging (8-wave GEMM3), ld = KP_
template <int ROWS>
__device__ __forceinline__ void stage512(const f16* __restrict__ src,
                                         int row0, int k0, f16* lds, int tid) {
  constexpr int ISSUES = ROWS / 64;
  const int l = tid & 63, w = tid >> 6;
#pragma unroll
  for (int i = 0; i < ISSUES; ++i) {
    int chunk = i * 8192 + w * 1024;
    int o = chunk + l * 16;
    int r = o >> 7;
    int p = o ^ ((r & 7) << 4);
    int c = (p & 127) >> 1;
    const f16* g = src + (size_t)(row0 + r) * KP_ + k0 + c;
    __builtin_amdgcn_global_load_lds(
        (const __attribute__((address_space(1))) void*)g,
        (__attribute__((address_space(3))) void*)(lds + (chunk >> 1)),
        16, 0, 0);
  }
}

// ---------------------------------------------------------------------------
// NT GEMM (GEMM1/GEMM2): A (M x K) @ Bt (N x K)^T, 128x128 tile, 4 waves.
// out = tanh(acc + bias) stored f16 (bias zero for col >= blim).
__global__ __launch_bounds__(256) void gemm_nt(
    const f16* __restrict__ A, int lda, const f16* __restrict__ Bt, int ldb,
    const float* __restrict__ bias, int blim, f16* __restrict__ outh, int ldo,
    int Ksteps, int nbn) {
  __shared__ __align__(16) f16 smem[(128 + 128) * 64];
  f16* As = smem;
  f16* Bs = As + 128 * 64;

  const int tid = threadIdx.x;
  const int l = tid & 63, wid = tid >> 6;
  const int wr = wid >> 1, wc = wid & 1;
  const int l15 = l & 15, lg = l >> 4;
  const int bm = blockIdx.x / nbn, bn = blockIdx.x % nbn;
  const int m0 = bm * 128, n0 = bn * 128;

  f32x4 acc[4][4];
#pragma unroll
  for (int mi = 0; mi < 4; ++mi)
#pragma unroll
    for (int ni = 0; ni < 4; ++ni) acc[mi][ni] = (f32x4){0.f, 0.f, 0.f, 0.f};

  for (int ks = 0; ks < Ksteps; ++ks) {
    const int k0 = ks * 64;
    stage_tile<128>(A, lda, m0, k0, As, tid);
    stage_tile<128>(Bt, ldb, n0, k0, Bs, tid);
    __syncthreads();
#pragma unroll
    for (int kk = 0; kk < 64; kk += 32) {
      const int kb = (kk + lg * 8) * 2;
      f16x8 af[4];
#pragma unroll
      for (int mi = 0; mi < 4; ++mi)
        af[mi] = frag_ld(As, wr * 64 + mi * 16 + l15, kb);
#pragma unroll
      for (int ni = 0; ni < 4; ++ni) {
        f16x8 bf = frag_ld(Bs, wc * 64 + ni * 16 + l15, kb);
#pragma unroll
        for (int mi = 0; mi < 4; ++mi)
          acc[mi][ni] = __builtin_amdgcn_mfma_f32_16x16x32_f16(af[mi], bf,
                                                               acc[mi][ni], 0, 0, 0);
      }
    }
    __syncthreads();
  }

  // C/D layout: col = lane&15, row = (lane>>4)*4 + j
#pragma unroll
  for (int ni = 0; ni < 4; ++ni) {
    int col = n0 + wc * 64 + ni * 16 + l15;
    float bv = (col < blim) ? bias[col] : 0.f;
#pragma unroll
    for (int mi = 0; mi < 4; ++mi) {
      int r0 = m0 + wr * 64 + mi * 16 + lg * 4;
#pragma unroll
      for (int j = 0; j < 4; ++j)
        outh[(size_t)(r0 + j) * ldo + col] = (f16)tanhf(acc[mi][ni][j] + bv);
    }
  }
}

// ---------------------------------------------------------------------------
// GEMM3 fused: w = (h2 @ W3t[:6528]^T + b3) group-6-contracted with v.
// 256x192 tile, BK=64, 8 waves (2x4), double-buffered LDS, raw barriers,
// counted vmcnt(7) (T4), phase-split MFMA clusters with setprio (T3+T5).
#define G3_KSTEPS 104
__global__ __launch_bounds__(512) void gemm3_kernel(
    const f16* __restrict__ A,        // h2: 8192 x KP_
    const f16* __restrict__ Bt,       // W3t: 6528 x KP_
    const float* __restrict__ bias,   // b3
    const float* __restrict__ vv,     // 8192 x 8
    float* __restrict__ w) {          // 8192 x 1088
  __shared__ __align__(16) unsigned char smem[114688];
  f16* Asb = (f16*)smem;              // 2 x 256*64
  f16* Bsb = Asb + 2 * 256 * 64;      // 2 x 192*64

  const int tid = threadIdx.x;
  const int l = tid & 63, wid = tid >> 6;
  const int wr = wid >> 2, wc = wid & 3;         // 2 x 4 wave grid
  const int l15 = l & 15, lg = l >> 4;
  const int wg = (blockIdx.x & 7) * 136 + (blockIdx.x >> 3);  // XCD swizzle (1088%8==0)
  const int bm = wg / 34, bn = wg % 34;
  const int m0 = bm * 256, n0 = bn * 192;

  f32x4 acc[8][3];
#pragma unroll
  for (int mi = 0; mi < 8; ++mi)
#pragma unroll
    for (int ni = 0; ni < 3; ++ni) acc[mi][ni] = (f32x4){0.f, 0.f, 0.f, 0.f};

  // prologue: tiles 0 and 1 in flight
  stage512<256>(A, m0, 0, Asb, tid);
  stage512<192>(Bt, n0, 0, Bsb, tid);
  stage512<256>(A, m0, 64, Asb + 256 * 64, tid);
  stage512<192>(Bt, n0, 64, Bsb + 192 * 64, tid);
  VMCNT(7);                                      // tile 0 landed
  __builtin_amdgcn_s_barrier();

#pragma unroll 1
  for (int ks = 0; ks < G3_KSTEPS; ++ks) {
    const f16* Ac = Asb + (ks & 1) * 256 * 64;
    const f16* Bc = Bsb + (ks & 1) * 192 * 64;
#pragma unroll
    for (int kki = 0; kki < 2; ++kki) {
      const int kb = (kki * 32 + lg * 8) * 2;
      f16x8 bf[3], af[4];
      // ---- phase A: mi 0..3 (+ B frags for this kk) ----
#pragma unroll
      for (int ni = 0; ni < 3; ++ni)
        bf[ni] = frag_ld(Bc, wc * 48 + ni * 16 + l15, kb);
#pragma unroll
      for (int mi = 0; mi < 4; ++mi)
        af[mi] = frag_ld(Ac, wr * 128 + mi * 16 + l15, kb);
      __builtin_amdgcn_s_barrier();
      LGKMCNT0;
      __builtin_amdgcn_s_setprio(1);
#pragma unroll
      for (int mi = 0; mi < 4; ++mi)
#pragma unroll
        for (int ni = 0; ni < 3; ++ni)
          acc[mi][ni] = __builtin_amdgcn_mfma_f32_16x16x32_f16(af[mi], bf[ni],
                                                               acc[mi][ni], 0, 0, 0);
      __builtin_amdgcn_s_setprio(0);
      __builtin_amdgcn_s_barrier();
      // ---- phase B: mi 4..7 (B frags reused) ----
#pragma unroll
      for (int mi = 0; mi < 4; ++mi)
        af[mi] = frag_ld(Ac, wr * 128 + (mi + 4) * 16 + l15, kb);
      __builtin_amdgcn_s_barrier();
      LGKMCNT0;
      __builtin_amdgcn_s_setprio(1);
#pragma unroll
      for (int mi = 0; mi < 4; ++mi)
#pragma unroll
        for (int ni = 0; ni < 3; ++ni)
          acc[mi + 4][ni] = __builtin_amdgcn_mfma_f32_16x16x32_f16(af[mi], bf[ni],
                                                                   acc[mi + 4][ni], 0, 0, 0);
      __builtin_amdgcn_s_setprio(0);
      __builtin_amdgcn_s_barrier();
    }
    // ---- tail: prefetch tile ks+2 into the buffer we just finished reading ----
    if (ks + 1 < G3_KSTEPS) {
      __builtin_amdgcn_sched_barrier(0);
      if (ks + 2 < G3_KSTEPS) {
        f16* An = Asb + (ks & 1) * 256 * 64;
        f16* Bn = Bsb + (ks & 1) * 192 * 64;
        stage512<256>(A, m0, (ks + 2) * 64, An, tid);
        stage512<192>(Bt, n0, (ks + 2) * 64, Bn, tid);
        VMCNT(7);                                // tile ks+1 landed; 7 newer in flight
      } else {
        VMCNT(0);                                // drain last tile
      }
      __builtin_amdgcn_s_barrier();
    }
  }

  // ---- fused epilogue: LDS bounce in two 128-row halves ----
  float* Cl = (float*)smem;                      // [128][193] fp32
#pragma unroll
  for (int h = 0; h < 2; ++h) {
    __syncthreads();
    if (wr == h) {
#pragma unroll
      for (int ni = 0; ni < 3; ++ni) {
        int cl = wc * 48 + ni * 16 + l15;
        float bv = bias[n0 + cl];
#pragma unroll
        for (int mi = 0; mi < 8; ++mi) {
          int rl = mi * 16 + lg * 4;
#pragma unroll
          for (int j = 0; j < 4; ++j)
            Cl[(rl + j) * 193 + cl] = acc[mi][ni][j] + bv;
        }
      }
    }
    __syncthreads();
#pragma unroll
    for (int it = 0; it < 8; ++it) {
      int idx = it * 512 + tid;                  // 128 rows x 32 groups
      int r = idx >> 5, g = idx & 31;
      const float* vr = vv + (size_t)(m0 + h * 128 + r) * 8;
      float s = 0.f;
#pragma unroll
      for (int k = 0; k < 6; ++k) s += Cl[r * 193 + g * 6 + k] * vr[k];
      w[(size_t)(m0 + h * 128 + r) * NW_ + bn * 32 + g] = s;
    }
  }
}

// ---------------------------------------------------------------------------
// dil/shift strip (12 x KP_ f16, transposed from W3 cols 6528..6539), then v.
__global__ __launch_bounds__(256) void sv_kernel(const f16* __restrict__ h2,
                                                 const f16* __restrict__ dil12,
                                                 const float* __restrict__ b3,
                                                 const float* __restrict__ x,
                                                 float* __restrict__ vv) {
  __shared__ float red[12][4];
  int b = blockIdx.x, tid = threadIdx.x;
  int lane = tid & 63, wid = tid >> 6;
  float p[12];
#pragma unroll
  for (int j = 0; j < 12; ++j) p[j] = 0.f;
  for (int c = tid; c < KP_ / 8; c += 256) {     // 832 chunks of 8 f16
    f16x8 hv = *(const f16x8*)(h2 + (size_t)b * KP_ + c * 8);
#pragma unroll
    for (int j = 0; j < 12; ++j) {
      f16x8 wv = *(const f16x8*)(dil12 + (size_t)j * KP_ + c * 8);
      float s = 0.f;
#pragma unroll
      for (int e = 0; e < 8; ++e) s += (float)hv[e] * (float)wv[e];
      p[j] += s;
    }
  }
#pragma unroll
  for (int j = 0; j < 12; ++j) {
    float v = p[j];
    for (int off = 32; off; off >>= 1) v += __shfl_down(v, off, 64);
    if (lane == 0) red[j][wid] = v;
  }
  __syncthreads();
  if (tid < 6) {
    int j = tid;
    float dil = red[j][0] + red[j][1] + red[j][2] + red[j][3] + b3[MK_ + j];
    float sh  = red[6 + j][0] + red[6 + j][1] + red[6 + j][2] + red[6 + j][3] + b3[MK_ + 6 + j];
    float s = x[(size_t)(B_ - 1) * XCOLS_ + INF_];
    float sv = s * dil + sh;
    vv[(size_t)b * 8 + j] = (j < 3) ? cosf(sv * (float)j) : sinf(sv * (float)(j - 3));
  }
}

// ---------------------------------------------------------------------------
// out[b,o] = sum_i inp[b,i] * w[b, i*64+o] + w[b, 1024+o]
__global__ __launch_bounds__(256) void out_kernel(const float* __restrict__ x,
                                                  const float* __restrict__ w,
                                                  float* __restrict__ out) {
  int wid = threadIdx.x >> 6, lane = threadIdx.x & 63;
  int b = blockIdx.x * 4 + wid;
  const float* wr = w + (size_t)b * NW_;
  const float* xr = x + (size_t)b * XCOLS_;
  float acc = wr[1024 + lane];
#pragma unroll
  for (int i = 0; i < 16; ++i) acc += xr[i] * wr[i * 64 + lane];
  out[(size_t)b * 64 + lane] = acc;
}

// ---------------------------------------------------------------------------
extern "C" void kernel_launch(void* const* d_in, const int* in_sizes, int n_in,
                              void* d_out, int out_size, void* d_ws, size_t ws_size,
                              hipStream_t stream) {
  const float* x  = (const float*)d_in[0];
  const float* W1 = (const float*)d_in[1];
  const float* b1 = (const float*)d_in[2];
  const float* W2 = (const float*)d_in[3];
  const float* b2 = (const float*)d_in[4];
  const float* W3 = (const float*)d_in[5];
  const float* b3 = (const float*)d_in[6];
  float* out = (float*)d_out;

  char* ws = (char*)d_ws;
  f16*   zh  = (f16*)(ws);                        //  2,097,152 B (reused for dil12 after GEMM1)
  f16*   W1t = (f16*)(ws + 2097152);              //    262,144 B  (1024 x 128)
  f16*   W2t = (f16*)(ws + 2359296);              // 13,631,488 B  (6656 x 1024)
  f16*   W3t = (f16*)(ws + 15990784);             // 86,900,736 B  (6528 x 6656)
  f16*   h1  = (f16*)(ws + 102891520);            // 16,777,216 B  (8192 x 1024)
  f16*   h2  = (f16*)(ws + 119668736);            //109,051,904 B  (8192 x 6656)
  float* vv  = (float*)(ws + 228720640);          //    262,144 B  (8192 x 8)
  float* w   = (float*)(ws + 228982784);          // 35,651,584 B  (8192 x 1088)
  f16*   dil12 = zh;                              // 12 x 6656 f16 = 159,744 B

  zh_kernel<<<4096, 256, 0, stream>>>(x, zh);
  tconv_kernel<<<dim3(2, 16),    256, 0, stream>>>(W1, W1t, 128,  1024, 1024, 128,  1024);
  tconv_kernel<<<dim3(16, 104),  256, 0, stream>>>(W2, W2t, 1024, CS_,  CS_,  1024, KP_);
  tconv_kernel<<<dim3(104, 102), 256, 0, stream>>>(W3, W3t, CS_,  CS_,  N3_,  KP_,  N3_);

  // GEMM1: h1 = tanh(zh @ W1 + b1)   (M=8192, N=1024, K=128) — consumes zh
  gemm_nt<<<(1024 / 128) * (B_ / 128), 256, 0, stream>>>(
      zh, 128, W1t, 128, b1, 1024, h1, 1024, 2, 1024 / 128);
  // dil/shift strip: W3 cols 6528..6539 transposed into (dead) zh region
  tconv_kernel<<<dim3(104, 1),   256, 0, stream>>>(W3 + MK_, dil12, CS_, CS_, 12, KP_, 12);
  // GEMM2: h2 = tanh(h1 @ W2 + b2)   (M=8192, N=6656pad, K=1024)
  gemm_nt<<<(KP_ / 128) * (B_ / 128), 256, 0, stream>>>(
      h1, 1024, W2t, 1024, b2, CS_, h2, KP_, 16, KP_ / 128);
  // dilation/shift + v
  sv_kernel<<<B_, 256, 0, stream>>>(h2, dil12, b3, x, vv);
  // GEMM3 fused (8-wave, 256x192, counted-vmcnt pipeline)
  gemm3_kernel<<<(B_ / 256) * (N3_ / 192), 512, 0, stream>>>(h2, W3t, b3, vv, w);
  // final einsum
  out_kernel<<<B_ / 4, 256, 0, stream>>>(x, w, out);
}